// Round 9
// baseline (2563.143 us; speedup 1.0000x reference)
//
#include <hip/hip_runtime.h>
#include <math.h>

#define N_NODES 100000
#define N_EDGES 3200000
#define BSHIFT 6
#define NBUCK 1563           // ceil(100000/64) coarse buckets (src>>6)
#define NBLK_E 512           // edge-pass blocks
#define EPB 6250             // edges per edge-pass block (512*6250 = 3.2M exactly)

typedef _Float16 half8 __attribute__((ext_vector_type(8)));
typedef float f32x4 __attribute__((ext_vector_type(4)));

__device__ __forceinline__ void gload16(const void* gsrc, void* ldst) {
    __builtin_amdgcn_global_load_lds(
        (const __attribute__((address_space(1))) unsigned int*)gsrc,
        (__attribute__((address_space(3))) unsigned int*)ldst,
        16, 0, 0);
}

// ---------------------------------------------------------------------------
// K0: pack feats[N,128] (f16) = concat(x[124], pos[3], z[1])
// ---------------------------------------------------------------------------
__global__ __launch_bounds__(256) void pack_kernel(
    const float* __restrict__ x, const float* __restrict__ pos,
    const float* __restrict__ z, _Float16* __restrict__ feats)
{
    int idx = blockIdx.x * blockDim.x + threadIdx.x;
    if (idx >= N_NODES * 128) return;
    int n = idx >> 7, f = idx & 127;
    float v;
    if (f < 124)      v = x[n * 124 + f];
    else if (f < 127) v = pos[n * 3 + (f - 124)];
    else              v = z[n];
    feats[idx] = (_Float16)v;
}

// ---------------------------------------------------------------------------
// weight prep: W[K,256] f32 -> WT [256,K] f16
// ---------------------------------------------------------------------------
__global__ __launch_bounds__(256) void wprep_kernel(
    const float* __restrict__ W, int K, _Float16* __restrict__ WT)
{
    int idx = blockIdx.x * blockDim.x + threadIdx.x;
    if (idx >= K * 256) return;
    int k = idx >> 8, c = idx & 255;
    WT[c * K + k] = (_Float16)W[idx];
}

// ---------------------------------------------------------------------------
// K1: coarse histogram per edge-block, all atomics in LDS.
// gcnt[blk][bucket] (row-major, coalesced write)
// ---------------------------------------------------------------------------
__global__ __launch_bounds__(256) void coarse_hist_kernel(
    const int* __restrict__ ei, int* __restrict__ gcnt)
{
    __shared__ int bins[NBUCK];
    int t = threadIdx.x, blk = blockIdx.x;
    for (int b = t; b < NBUCK; b += 256) bins[b] = 0;
    __syncthreads();
    int base = blk * EPB;
    #pragma unroll
    for (int k = 0; k < 25; ++k) {
        int i = t + k * 256;
        if (i < EPB) {
            int src = __builtin_nontemporal_load(&ei[base + i]);
            atomicAdd(&bins[src >> BSHIFT], 1);
        }
    }
    __syncthreads();
    for (int b = t; b < NBUCK; b += 256)
        gcnt[blk * NBUCK + b] = bins[b];
}

// ---------------------------------------------------------------------------
// K2a: per-bucket totals (column sums of gcnt)
// ---------------------------------------------------------------------------
__global__ __launch_bounds__(256) void bucket_tot_kernel(
    const int* __restrict__ gcnt, int* __restrict__ btot)
{
    __shared__ int red[4];
    int b = blockIdx.x, t = threadIdx.x;
    int s = 0;
    for (int blk = t; blk < NBLK_E; blk += 256) s += gcnt[blk * NBUCK + b];
    #pragma unroll
    for (int off = 32; off > 0; off >>= 1) s += __shfl_xor(s, off, 64);
    if ((t & 63) == 0) red[t >> 6] = s;
    __syncthreads();
    if (t == 0) btot[b] = red[0] + red[1] + red[2] + red[3];
}

// ---------------------------------------------------------------------------
// K2b: exclusive scan of 1563 bucket totals -> bbase[0..NBUCK]
// 1024 threads x 2 elements
// ---------------------------------------------------------------------------
__global__ __launch_bounds__(1024) void scan_buckets_kernel(
    const int* __restrict__ btot, int* __restrict__ bbase)
{
    __shared__ int s[1024];
    int t = threadIdx.x;
    int i0 = 2 * t, i1 = 2 * t + 1;
    int v0 = (i0 < NBUCK) ? btot[i0] : 0;
    int v1 = (i1 < NBUCK) ? btot[i1] : 0;
    int sum = v0 + v1;
    s[t] = sum;
    __syncthreads();
    for (int off = 1; off < 1024; off <<= 1) {
        int o = (t >= off) ? s[t - off] : 0;
        __syncthreads();
        s[t] += o;
        __syncthreads();
    }
    int excl = s[t] - sum;
    if (i0 < NBUCK) bbase[i0] = excl;
    if (i1 < NBUCK) bbase[i1] = excl + v0;
    if (i0 == NBUCK - 1) bbase[NBUCK] = excl + v0;
    if (i1 == NBUCK - 1) bbase[NBUCK] = excl + v0 + v1;
}

// ---------------------------------------------------------------------------
// K2c: per-bucket column scan over blocks:
//   gbase[blk][b] = bbase[b] + sum_{blk'<blk} gcnt[blk'][b]
// ---------------------------------------------------------------------------
__global__ __launch_bounds__(256) void colscan_kernel(
    const int* __restrict__ gcnt, const int* __restrict__ bbase,
    int* __restrict__ gbase)
{
    __shared__ int s[NBLK_E];
    int b = blockIdx.x, t = threadIdx.x;
    int v0 = gcnt[t * NBUCK + b];
    int v1 = gcnt[(t + 256) * NBUCK + b];
    s[t] = v0; s[t + 256] = v1;
    __syncthreads();
    for (int off = 1; off < NBLK_E; off <<= 1) {
        int o0 = (t >= off) ? s[t - off] : 0;
        int o1 = (t + 256 >= off) ? s[t + 256 - off] : 0;
        __syncthreads();
        s[t] += o0; s[t + 256] += o1;
        __syncthreads();
    }
    int bb = bbase[b];
    gbase[t * NBUCK + b] = bb + s[t] - v0;
    gbase[(t + 256) * NBUCK + b] = bb + s[t + 256] - v1;
}

// ---------------------------------------------------------------------------
// K3: bucket scatter (LDS-atomic ranks): bucketed[pos] = dst | (src&63)<<17
// ---------------------------------------------------------------------------
__global__ __launch_bounds__(256) void bucket_scatter_kernel(
    const int* __restrict__ ei, const int* __restrict__ gbase,
    unsigned int* __restrict__ bucketed)
{
    __shared__ int myoff[NBUCK];
    __shared__ int bins[NBUCK];
    int t = threadIdx.x, blk = blockIdx.x;
    for (int b = t; b < NBUCK; b += 256) {
        myoff[b] = gbase[blk * NBUCK + b];
        bins[b] = 0;
    }
    __syncthreads();
    int base = blk * EPB;
    #pragma unroll
    for (int k = 0; k < 25; ++k) {
        int i = t + k * 256;
        if (i < EPB) {
            int e = base + i;
            int src = __builtin_nontemporal_load(&ei[e]);
            int dst = __builtin_nontemporal_load(&ei[N_EDGES + e]);
            int b = src >> BSHIFT;
            int r = atomicAdd(&bins[b], 1);
            unsigned int packed = (unsigned int)dst |
                                  ((unsigned int)(src & 63) << 17);
            __builtin_nontemporal_store(packed, &bucketed[myoff[b] + r]);
        }
    }
}

// ---------------------------------------------------------------------------
// K4: per-bucket LDS f32 accumulation + L2 normalize -> h0 (f16)
// One block per 64-node bucket. acc[64][132] f32 (33.8 KB -> 4 blocks/CU).
// Each half-wave processes one edge: gather dst row (uint2/lane), 4x
// ds-atomic-add with bank-rotated layout perm(f) = (f&~3)|(((f&3)+(f>>5))&3)
// -> every 64-lane ds_add hits each bank exactly twice (free, m136).
// ---------------------------------------------------------------------------
__global__ __launch_bounds__(256) void aggacc_kernel(
    const int* __restrict__ bbase, const unsigned int* __restrict__ bucketed,
    const uint2* __restrict__ featsU2, _Float16* __restrict__ h0)
{
    __shared__ float acc[64 * 132];

    int t = threadIdx.x, b = blockIdx.x;
    for (int i = t; i < 64 * 132; i += 256) acc[i] = 0.f;
    __syncthreads();

    int segs = bbase[b], cnt = bbase[b + 1] - segs;
    int half = t >> 5;            // half-wave id 0..7
    int s = t & 31;               // lane covers feats 4s..4s+3
    int rot = s >> 3;             // bank rotation 0..3
    union { unsigned int ui; _Float16 f[2]; } cu;

#define EDGE_ACC(P)                                                          \
    {                                                                        \
        int dst = (int)((P) & 0x1FFFFu);                                     \
        int nl = (int)(((P) >> 17) & 63u);                                   \
        uint2 u = featsU2[(long long)dst * 32 + s];                          \
        float v0, v1, v2, v3;                                                \
        cu.ui = u.x; v0 = (float)cu.f[0]; v1 = (float)cu.f[1];               \
        cu.ui = u.y; v2 = (float)cu.f[0]; v3 = (float)cu.f[1];               \
        float* bp = &acc[nl * 132 + s * 4];                                  \
        atomicAdd(&bp[rot], v0);                                             \
        atomicAdd(&bp[(rot + 1) & 3], v1);                                   \
        atomicAdd(&bp[(rot + 2) & 3], v2);                                   \
        atomicAdd(&bp[(rot + 3) & 3], v3);                                   \
    }

    int i = half;
    for (; i + 8 < cnt; i += 16) {
        unsigned int p0 = bucketed[segs + i];
        unsigned int p1 = bucketed[segs + i + 8];
        EDGE_ACC(p0);
        EDGE_ACC(p1);
    }
    for (; i < cnt; i += 8) {
        unsigned int p = bucketed[segs + i];
        EDGE_ACC(p);
    }
#undef EDGE_ACC
    __syncthreads();

    // normalize: thread handles node nl = t>>2, feat quarter q = t&3
    int nl = t >> 2, q = t & 3;
    int node = b * 64 + nl;
    float vals[32];
    float ss = 0.f;
    #pragma unroll
    for (int k = 0; k < 32; ++k) {
        // feat f = q*32 + k stored at slot (f&~3) | (((f&3)+q)&3)
        int idx = nl * 132 + q * 32 + (k & ~3) + (((k & 3) + q) & 3);
        float v = acc[idx];
        vals[k] = v;
        ss += v * v;
    }
    ss += __shfl_xor(ss, 1, 64);
    ss += __shfl_xor(ss, 2, 64);
    float inv = 1.0f / sqrtf(ss);
    if (node < N_NODES) {
        _Float16* op = &h0[(long long)node * 128 + q * 32];
        #pragma unroll
        for (int k = 0; k < 8; ++k) {
            union { unsigned int u; _Float16 f[2]; } o0, o1;
            o0.f[0] = (_Float16)(vals[k * 4 + 0] * inv);
            o0.f[1] = (_Float16)(vals[k * 4 + 1] * inv);
            o1.f[0] = (_Float16)(vals[k * 4 + 2] * inv);
            o1.f[1] = (_Float16)(vals[k * 4 + 3] * inv);
            uint2 ov; ov.x = o0.u; ov.y = o1.u;
            *reinterpret_cast<uint2*>(op + k * 4) = ov;
        }
    }
}

// ---------------------------------------------------------------------------
// K5: FUSED MLP (3 layers + W4 dot) per 64-row block; acts live in LDS
// ---------------------------------------------------------------------------
__global__ __launch_bounds__(256) void fused_mlp_kernel(
    const _Float16* __restrict__ h0,    // [M][128]
    const _Float16* __restrict__ WT1,   // [256][128]
    const float* __restrict__ b1,
    const _Float16* __restrict__ WT2,   // [256][256]
    const float* __restrict__ b2,
    const _Float16* __restrict__ WT3,   // [256][256]
    const float* __restrict__ b3,
    const float* __restrict__ W4,       // [256]
    float* __restrict__ partials, int M)
{
    __shared__ __align__(16) _Float16 sA[8 * 2048];   // 32 KB: 8 chunks 64x32
    __shared__ __align__(16) _Float16 sB[256 * 32];   // 16 KB
    __shared__ float redf[4];

    const int t = threadIdx.x;
    const int row0 = blockIdx.x * 64;

    const int ar = t >> 2, ap = t & 3;
    const int ag = ap ^ ((ar >> 1) & 3);
    int arow = row0 + ar; if (arow > M - 1) arow = M - 1;
    const _Float16* aSrc = h0 + (long long)arow * 128 + ag * 8;

    const int bc0 = t >> 2;
    const int gb = ap ^ ((bc0 >> 1) & 3);

    const int w = t >> 6, lane = t & 63;
    const int wr = w >> 1, wc = w & 1;
    const int lrow = lane & 15, g = lane >> 4;

    unsigned int offA[2], offB[8];
    #pragma unroll
    for (int rt = 0; rt < 2; ++rt) {
        int r = wr * 32 + rt * 16 + lrow;
        offA[rt] = r * 64 + (g ^ ((r >> 1) & 3)) * 16;
    }
    #pragma unroll
    for (int ct = 0; ct < 8; ++ct) {
        int cidx = wc * 128 + ct * 16 + lrow;
        offB[ct] = cidx * 64 + (g ^ ((cidx >> 1) & 3)) * 16;
    }

    f32x4 acc[2][8];
    #pragma unroll
    for (int i = 0; i < 2; ++i)
        #pragma unroll
        for (int j = 0; j < 8; ++j)
            acc[i][j] = (f32x4){0.f, 0.f, 0.f, 0.f};

#define STORE_ACTS(BIAS)                                                     \
    {                                                                        \
        _Pragma("unroll")                                                    \
        for (int ct = 0; ct < 8; ++ct) {                                     \
            int col = wc * 128 + ct * 16 + lrow;                             \
            float bb = (BIAS)[col];                                          \
            int chk = col >> 5, kk = col & 31;                               \
            int kg = kk >> 3, ke = kk & 7;                                   \
            _Pragma("unroll")                                                \
            for (int rt = 0; rt < 2; ++rt) {                                 \
                _Pragma("unroll")                                            \
                for (int jj = 0; jj < 4; ++jj) {                             \
                    int rowl = wr * 32 + rt * 16 + g * 4 + jj;               \
                    int slot = kg ^ ((rowl >> 1) & 3);                       \
                    sA[chk * 2048 + rowl * 32 + slot * 8 + ke] =             \
                        (_Float16)fmaxf(acc[rt][ct][jj] + bb, 0.f);          \
                    acc[rt][ct][jj] = 0.f;                                   \
                }                                                            \
            }                                                                \
        }                                                                    \
    }

#define MFMA_CHUNK(KC)                                                       \
    {                                                                        \
        half8 a[2], b[8];                                                    \
        _Pragma("unroll")                                                    \
        for (int rt = 0; rt < 2; ++rt)                                       \
            a[rt] = *reinterpret_cast<const half8*>(                         \
                (const char*)sA + (KC) * 4096 + offA[rt]);                   \
        _Pragma("unroll")                                                    \
        for (int ct = 0; ct < 8; ++ct)                                       \
            b[ct] = *reinterpret_cast<const half8*>(                         \
                (const char*)sB + offB[ct]);                                 \
        _Pragma("unroll")                                                    \
        for (int rt = 0; rt < 2; ++rt)                                       \
            _Pragma("unroll")                                                \
            for (int ct = 0; ct < 8; ++ct)                                   \
                acc[rt][ct] = __builtin_amdgcn_mfma_f32_16x16x32_f16(        \
                    a[rt], b[ct], acc[rt][ct], 0, 0, 0);                     \
    }

    // layer 1: A from global h0 (K=128, 4 chunks)
    #pragma unroll
    for (int kc = 0; kc < 4; ++kc) {
        __syncthreads();
        gload16(aSrc + kc * 32, (char*)sA + kc * 4096 + t * 16);
        #pragma unroll
        for (int j = 0; j < 4; ++j)
            gload16(WT1 + (long long)(bc0 + j * 64) * 128 + gb * 8 + kc * 32,
                    (char*)sB + j * 4096 + t * 16);
        __syncthreads();
        MFMA_CHUNK(kc);
    }
    __syncthreads();
    STORE_ACTS(b1);

    // layer 2
    #pragma unroll
    for (int kc = 0; kc < 8; ++kc) {
        __syncthreads();
        #pragma unroll
        for (int j = 0; j < 4; ++j)
            gload16(WT2 + (long long)(bc0 + j * 64) * 256 + gb * 8 + kc * 32,
                    (char*)sB + j * 4096 + t * 16);
        __syncthreads();
        MFMA_CHUNK(kc);
    }
    __syncthreads();
    STORE_ACTS(b2);

    // layer 3
    #pragma unroll
    for (int kc = 0; kc < 8; ++kc) {
        __syncthreads();
        #pragma unroll
        for (int j = 0; j < 4; ++j)
            gload16(WT3 + (long long)(bc0 + j * 64) * 256 + gb * 8 + kc * 32,
                    (char*)sB + j * 4096 + t * 16);
        __syncthreads();
        MFMA_CHUNK(kc);
    }

    // epilogue: bias+relu, dot W4, block reduce
    float sum = 0.f;
    #pragma unroll
    for (int ct = 0; ct < 8; ++ct) {
        int col = wc * 128 + ct * 16 + lrow;
        float bb = b3[col];
        float w4 = W4[col];
        #pragma unroll
        for (int rt = 0; rt < 2; ++rt) {
            #pragma unroll
            for (int jj = 0; jj < 4; ++jj) {
                int row = row0 + wr * 32 + rt * 16 + g * 4 + jj;
                if (row < M) {
                    float v = fmaxf(acc[rt][ct][jj] + bb, 0.f);
                    sum += v * w4;
                }
            }
        }
    }
    #pragma unroll
    for (int off = 32; off > 0; off >>= 1) sum += __shfl_xor(sum, off, 64);
    if (lane == 0) redf[w] = sum;
    __syncthreads();
    if (t == 0) partials[blockIdx.x] = redf[0] + redf[1] + redf[2] + redf[3];
#undef STORE_ACTS
#undef MFMA_CHUNK
}

// ---------------------------------------------------------------------------
// K6: final mean: out = sum(partials)/N + b4
// ---------------------------------------------------------------------------
__global__ __launch_bounds__(256) void final_kernel(
    const float* __restrict__ partials, int n,
    const float* __restrict__ b4, float* __restrict__ out)
{
    __shared__ float buf[256];
    float s = 0.f;
    for (int i = threadIdx.x; i < n; i += 256) s += partials[i];
    buf[threadIdx.x] = s;
    __syncthreads();
    for (int off = 128; off > 0; off >>= 1) {
        if (threadIdx.x < off) buf[threadIdx.x] += buf[threadIdx.x + off];
        __syncthreads();
    }
    if (threadIdx.x == 0) out[0] = buf[0] / (float)N_NODES + b4[0];
}

// ---------------------------------------------------------------------------
extern "C" void kernel_launch(void* const* d_in, const int* in_sizes, int n_in,
                              void* d_out, int out_size, void* d_ws, size_t ws_size,
                              hipStream_t stream)
{
    const float* x   = (const float*)d_in[0];
    const float* pos = (const float*)d_in[1];
    const float* z   = (const float*)d_in[2];
    const int*   ei  = (const int*)d_in[3];
    const float* W1  = (const float*)d_in[4];
    const float* b1  = (const float*)d_in[5];
    const float* W2  = (const float*)d_in[6];
    const float* b2  = (const float*)d_in[7];
    const float* W3  = (const float*)d_in[8];
    const float* b3  = (const float*)d_in[9];
    const float* W4  = (const float*)d_in[10];
    const float* b4  = (const float*)d_in[11];
    float* out = (float*)d_out;

    char* ws = (char*)d_ws;
    _Float16*     feats    = (_Float16*)    (ws);              //  25,600,000
    _Float16*     h0       = (_Float16*)    (ws + 25600000);   //  25,600,000
    int*          gcnt     = (int*)         (ws + 51200000);   //   3,201,024
    int*          gbase    = (int*)         (ws + 54401024);   //   3,201,024
    int*          btot     = (int*)         (ws + 57602048);   //       6,252
    int*          bbase    = (int*)         (ws + 57608304);   //       6,256
    unsigned int* bucketed = (unsigned int*)(ws + 57614560);   //  12,800,000
    _Float16*     WT1      = (_Float16*)    (ws + 70414560);   //      65,536
    _Float16*     WT2      = (_Float16*)    (ws + 70480096);   //     131,072
    _Float16*     WT3      = (_Float16*)    (ws + 70611168);   //     131,072
    float*        partials = (float*)       (ws + 70742240);   //       6,252

    const int gblocks = (N_NODES + 63) / 64;   // 1563

    // weight prep
    wprep_kernel<<<(128 * 256 + 255) / 256, 256, 0, stream>>>(W1, 128, WT1);
    wprep_kernel<<<(256 * 256 + 255) / 256, 256, 0, stream>>>(W2, 256, WT2);
    wprep_kernel<<<(256 * 256 + 255) / 256, 256, 0, stream>>>(W3, 256, WT3);

    // pack features (f16)
    pack_kernel<<<(N_NODES * 128 + 255) / 256, 256, 0, stream>>>(x, pos, z, feats);

    // CSR build via two-level bucketing (LDS atomics only)
    coarse_hist_kernel<<<NBLK_E, 256, 0, stream>>>(ei, gcnt);
    bucket_tot_kernel<<<NBUCK, 256, 0, stream>>>(gcnt, btot);
    scan_buckets_kernel<<<1, 1024, 0, stream>>>(btot, bbase);
    colscan_kernel<<<NBUCK, 256, 0, stream>>>(gcnt, bbase, gbase);
    bucket_scatter_kernel<<<NBLK_E, 256, 0, stream>>>(ei, gbase, bucketed);

    // per-bucket LDS accumulate + normalize -> h0 (f16)
    aggacc_kernel<<<NBUCK, 256, 0, stream>>>(bbase, bucketed, (const uint2*)feats, h0);

    // fused MLP (3 layers + W4 dot) -> partials
    fused_mlp_kernel<<<gblocks, 256, 0, stream>>>(
        h0, WT1, b1, WT2, b2, WT3, b3, W4, partials, N_NODES);

    // final mean
    final_kernel<<<1, 256, 0, stream>>>(partials, gblocks, b4, out);
}

// Round 10
// 352.519 us; speedup vs baseline: 7.2709x; 7.2709x over previous
//
#include <hip/hip_runtime.h>
#include <math.h>

#define N_NODES 100000
#define N_EDGES 3200000
#define BSHIFT 6
#define NBUCK 1563           // ceil(100000/64) coarse buckets (src>>6)
#define NBLK_E 512           // edge-pass blocks
#define EPB 6250             // edges per edge-pass block (512*6250 = 3.2M exactly)
#define CAP 3072             // max edges per 64-node bucket (mean 2048, sd ~45)

typedef _Float16 half8 __attribute__((ext_vector_type(8)));
typedef float f32x4 __attribute__((ext_vector_type(4)));

__device__ __forceinline__ void gload16(const void* gsrc, void* ldst) {
    __builtin_amdgcn_global_load_lds(
        (const __attribute__((address_space(1))) unsigned int*)gsrc,
        (__attribute__((address_space(3))) unsigned int*)ldst,
        16, 0, 0);
}

// ---------------------------------------------------------------------------
// K0: pack feats[N,128] (f16) = concat(x[124], pos[3], z[1])
// ---------------------------------------------------------------------------
__global__ __launch_bounds__(256) void pack_kernel(
    const float* __restrict__ x, const float* __restrict__ pos,
    const float* __restrict__ z, _Float16* __restrict__ feats)
{
    int idx = blockIdx.x * blockDim.x + threadIdx.x;
    if (idx >= N_NODES * 128) return;
    int n = idx >> 7, f = idx & 127;
    float v;
    if (f < 124)      v = x[n * 124 + f];
    else if (f < 127) v = pos[n * 3 + (f - 124)];
    else              v = z[n];
    feats[idx] = (_Float16)v;
}

// ---------------------------------------------------------------------------
// weight prep: W[K,256] f32 -> WT [256,K] f16
// ---------------------------------------------------------------------------
__global__ __launch_bounds__(256) void wprep_kernel(
    const float* __restrict__ W, int K, _Float16* __restrict__ WT)
{
    int idx = blockIdx.x * blockDim.x + threadIdx.x;
    if (idx >= K * 256) return;
    int k = idx >> 8, c = idx & 255;
    WT[c * K + k] = (_Float16)W[idx];
}

// ---------------------------------------------------------------------------
// K1: coarse histogram per edge-block, all atomics in LDS (int = native).
// ---------------------------------------------------------------------------
__global__ __launch_bounds__(256) void coarse_hist_kernel(
    const int* __restrict__ ei, int* __restrict__ gcnt)
{
    __shared__ int bins[NBUCK];
    int t = threadIdx.x, blk = blockIdx.x;
    for (int b = t; b < NBUCK; b += 256) bins[b] = 0;
    __syncthreads();
    int base = blk * EPB;
    #pragma unroll
    for (int k = 0; k < 25; ++k) {
        int i = t + k * 256;
        if (i < EPB) {
            int src = __builtin_nontemporal_load(&ei[base + i]);
            atomicAdd(&bins[src >> BSHIFT], 1);
        }
    }
    __syncthreads();
    for (int b = t; b < NBUCK; b += 256)
        gcnt[blk * NBUCK + b] = bins[b];
}

// ---------------------------------------------------------------------------
// K2a: per-bucket totals (column sums of gcnt)
// ---------------------------------------------------------------------------
__global__ __launch_bounds__(256) void bucket_tot_kernel(
    const int* __restrict__ gcnt, int* __restrict__ btot)
{
    __shared__ int red[4];
    int b = blockIdx.x, t = threadIdx.x;
    int s = 0;
    for (int blk = t; blk < NBLK_E; blk += 256) s += gcnt[blk * NBUCK + b];
    #pragma unroll
    for (int off = 32; off > 0; off >>= 1) s += __shfl_xor(s, off, 64);
    if ((t & 63) == 0) red[t >> 6] = s;
    __syncthreads();
    if (t == 0) btot[b] = red[0] + red[1] + red[2] + red[3];
}

// ---------------------------------------------------------------------------
// K2b: exclusive scan of 1563 bucket totals -> bbase[0..NBUCK]
// ---------------------------------------------------------------------------
__global__ __launch_bounds__(1024) void scan_buckets_kernel(
    const int* __restrict__ btot, int* __restrict__ bbase)
{
    __shared__ int s[1024];
    int t = threadIdx.x;
    int i0 = 2 * t, i1 = 2 * t + 1;
    int v0 = (i0 < NBUCK) ? btot[i0] : 0;
    int v1 = (i1 < NBUCK) ? btot[i1] : 0;
    int sum = v0 + v1;
    s[t] = sum;
    __syncthreads();
    for (int off = 1; off < 1024; off <<= 1) {
        int o = (t >= off) ? s[t - off] : 0;
        __syncthreads();
        s[t] += o;
        __syncthreads();
    }
    int excl = s[t] - sum;
    if (i0 < NBUCK) bbase[i0] = excl;
    if (i1 < NBUCK) bbase[i1] = excl + v0;
    if (i0 == NBUCK - 1) bbase[NBUCK] = excl + v0;
    if (i1 == NBUCK - 1) bbase[NBUCK] = excl + v0 + v1;
}

// ---------------------------------------------------------------------------
// K2c: per-bucket column scan over blocks
// ---------------------------------------------------------------------------
__global__ __launch_bounds__(256) void colscan_kernel(
    const int* __restrict__ gcnt, const int* __restrict__ bbase,
    int* __restrict__ gbase)
{
    __shared__ int s[NBLK_E];
    int b = blockIdx.x, t = threadIdx.x;
    int v0 = gcnt[t * NBUCK + b];
    int v1 = gcnt[(t + 256) * NBUCK + b];
    s[t] = v0; s[t + 256] = v1;
    __syncthreads();
    for (int off = 1; off < NBLK_E; off <<= 1) {
        int o0 = (t >= off) ? s[t - off] : 0;
        int o1 = (t + 256 >= off) ? s[t + 256 - off] : 0;
        __syncthreads();
        s[t] += o0; s[t + 256] += o1;
        __syncthreads();
    }
    int bb = bbase[b];
    gbase[t * NBUCK + b] = bb + s[t] - v0;
    gbase[(t + 256) * NBUCK + b] = bb + s[t + 256] - v1;
}

// ---------------------------------------------------------------------------
// K3: bucket scatter (LDS-atomic ranks): bucketed[pos] = dst | (src&63)<<17
// ---------------------------------------------------------------------------
__global__ __launch_bounds__(256) void bucket_scatter_kernel(
    const int* __restrict__ ei, const int* __restrict__ gbase,
    unsigned int* __restrict__ bucketed)
{
    __shared__ int myoff[NBUCK];
    __shared__ int bins[NBUCK];
    int t = threadIdx.x, blk = blockIdx.x;
    for (int b = t; b < NBUCK; b += 256) {
        myoff[b] = gbase[blk * NBUCK + b];
        bins[b] = 0;
    }
    __syncthreads();
    int base = blk * EPB;
    #pragma unroll
    for (int k = 0; k < 25; ++k) {
        int i = t + k * 256;
        if (i < EPB) {
            int e = base + i;
            int src = __builtin_nontemporal_load(&ei[e]);
            int dst = __builtin_nontemporal_load(&ei[N_EDGES + e]);
            int b = src >> BSHIFT;
            int r = atomicAdd(&bins[b], 1);
            unsigned int packed = (unsigned int)dst |
                                  ((unsigned int)(src & 63) << 17);
            __builtin_nontemporal_store(packed, &bucketed[myoff[b] + r]);
        }
    }
}

// ---------------------------------------------------------------------------
// K4: per-bucket LDS counting sort (int atomics only) + gather-aggregate +
// L2 normalize -> h0 (f16). One block per 64-node bucket, ~12.5 KB LDS ->
// all 1563 blocks co-resident (~6/CU, 24 waves). Wave handles 16 nodes;
// 16-edge main loop = 8 gathers in flight per lane (two half-waves).
// ---------------------------------------------------------------------------
__global__ __launch_bounds__(256) void sortagg_kernel(
    const int* __restrict__ bbase, const unsigned int* __restrict__ bucketed,
    const uint2* __restrict__ featsU2, _Float16* __restrict__ h0)
{
    __shared__ unsigned int srt[CAP];
    __shared__ int excl[64], cur[64];

    int t = threadIdx.x, b = blockIdx.x;
    int segs = bbase[b], cnt = bbase[b + 1] - segs;
    if (cnt > CAP) cnt = CAP;   // statistically never (slack ~22 sd)

    if (t < 64) cur[t] = 0;
    __syncthreads();

    // phase 1: fine histogram (coalesced read, native int LDS atomics)
    for (int i = t; i < cnt; i += 256)
        atomicAdd(&cur[(bucketed[segs + i] >> 17) & 63], 1);
    __syncthreads();

    // phase 2: scan 64 bins
    int v = (t < 64) ? cur[t] : 0;
    if (t < 64) excl[t] = v;
    __syncthreads();
    for (int off = 1; off < 64; off <<= 1) {
        int o = (t >= off && t < 64) ? excl[t - off] : 0;
        __syncthreads();
        if (t < 64) excl[t] += o;
        __syncthreads();
    }
    if (t < 64) { excl[t] -= v; cur[t] = excl[t]; }
    __syncthreads();

    // phase 3: counting-sort into srt (re-read global: coalesced, L2-hot)
    for (int i = t; i < cnt; i += 256) {
        unsigned int p = bucketed[segs + i];
        int r = atomicAdd(&cur[(p >> 17) & 63], 1);
        if (r < CAP) srt[r] = p & 0x1FFFFu;
    }
    __syncthreads();
    // node nl's edges: srt[excl[nl] .. cur[nl])

    // phase 4: aggregate per node (wave w owns nodes w*16 .. w*16+15)
    int w = t >> 6, lane = t & 63;
    int h = lane >> 5, s = lane & 31;
    const uint2* fb = featsU2 + s;
    union { unsigned int u; _Float16 f[2]; } c;

    for (int j = 0; j < 16; ++j) {
        int nl = w * 16 + j;
        int node = b * 64 + nl;
        if (node >= N_NODES) break;
        int start = excl[nl], end = cur[nl];
        float a0 = 0.f, a1 = 0.f, a2 = 0.f, a3 = 0.f;
        int i = start;
        for (; i + 16 <= end; i += 16) {
            int d0 = srt[i + h];
            int d1 = srt[i + 2 + h];
            int d2 = srt[i + 4 + h];
            int d3 = srt[i + 6 + h];
            int d4 = srt[i + 8 + h];
            int d5 = srt[i + 10 + h];
            int d6 = srt[i + 12 + h];
            int d7 = srt[i + 14 + h];
            uint2 u0 = fb[(long long)d0 * 32];
            uint2 u1 = fb[(long long)d1 * 32];
            uint2 u2 = fb[(long long)d2 * 32];
            uint2 u3 = fb[(long long)d3 * 32];
            uint2 u4 = fb[(long long)d4 * 32];
            uint2 u5 = fb[(long long)d5 * 32];
            uint2 u6 = fb[(long long)d6 * 32];
            uint2 u7 = fb[(long long)d7 * 32];
            c.u = u0.x; a0 += (float)c.f[0]; a1 += (float)c.f[1];
            c.u = u0.y; a2 += (float)c.f[0]; a3 += (float)c.f[1];
            c.u = u1.x; a0 += (float)c.f[0]; a1 += (float)c.f[1];
            c.u = u1.y; a2 += (float)c.f[0]; a3 += (float)c.f[1];
            c.u = u2.x; a0 += (float)c.f[0]; a1 += (float)c.f[1];
            c.u = u2.y; a2 += (float)c.f[0]; a3 += (float)c.f[1];
            c.u = u3.x; a0 += (float)c.f[0]; a1 += (float)c.f[1];
            c.u = u3.y; a2 += (float)c.f[0]; a3 += (float)c.f[1];
            c.u = u4.x; a0 += (float)c.f[0]; a1 += (float)c.f[1];
            c.u = u4.y; a2 += (float)c.f[0]; a3 += (float)c.f[1];
            c.u = u5.x; a0 += (float)c.f[0]; a1 += (float)c.f[1];
            c.u = u5.y; a2 += (float)c.f[0]; a3 += (float)c.f[1];
            c.u = u6.x; a0 += (float)c.f[0]; a1 += (float)c.f[1];
            c.u = u6.y; a2 += (float)c.f[0]; a3 += (float)c.f[1];
            c.u = u7.x; a0 += (float)c.f[0]; a1 += (float)c.f[1];
            c.u = u7.y; a2 += (float)c.f[0]; a3 += (float)c.f[1];
        }
        for (; i + 2 <= end; i += 2) {
            int d = srt[i + h];
            uint2 u = fb[(long long)d * 32];
            c.u = u.x; a0 += (float)c.f[0]; a1 += (float)c.f[1];
            c.u = u.y; a2 += (float)c.f[0]; a3 += (float)c.f[1];
        }
        if (i < end && h == 0) {
            int d = srt[i];
            uint2 u = fb[(long long)d * 32];
            c.u = u.x; a0 += (float)c.f[0]; a1 += (float)c.f[1];
            c.u = u.y; a2 += (float)c.f[0]; a3 += (float)c.f[1];
        }
        a0 += __shfl_xor(a0, 32, 64);
        a1 += __shfl_xor(a1, 32, 64);
        a2 += __shfl_xor(a2, 32, 64);
        a3 += __shfl_xor(a3, 32, 64);
        float ss = a0 * a0 + a1 * a1 + a2 * a2 + a3 * a3;
        #pragma unroll
        for (int off = 16; off > 0; off >>= 1) ss += __shfl_xor(ss, off, 64);
        float inv = 1.0f / sqrtf(ss);
        if (h == 0) {
            union { uint2 u; _Float16 f[4]; } o;
            o.f[0] = (_Float16)(a0 * inv); o.f[1] = (_Float16)(a1 * inv);
            o.f[2] = (_Float16)(a2 * inv); o.f[3] = (_Float16)(a3 * inv);
            *reinterpret_cast<uint2*>(&h0[(long long)node * 128 + s * 4]) = o.u;
        }
    }
}

// ---------------------------------------------------------------------------
// K5: FUSED MLP (3 layers + W4 dot) per 64-row block; acts live in LDS
// ---------------------------------------------------------------------------
__global__ __launch_bounds__(256) void fused_mlp_kernel(
    const _Float16* __restrict__ h0,    // [M][128]
    const _Float16* __restrict__ WT1,   // [256][128]
    const float* __restrict__ b1,
    const _Float16* __restrict__ WT2,   // [256][256]
    const float* __restrict__ b2,
    const _Float16* __restrict__ WT3,   // [256][256]
    const float* __restrict__ b3,
    const float* __restrict__ W4,       // [256]
    float* __restrict__ partials, int M)
{
    __shared__ __align__(16) _Float16 sA[8 * 2048];   // 32 KB: 8 chunks 64x32
    __shared__ __align__(16) _Float16 sB[256 * 32];   // 16 KB
    __shared__ float redf[4];

    const int t = threadIdx.x;
    const int row0 = blockIdx.x * 64;

    const int ar = t >> 2, ap = t & 3;
    const int ag = ap ^ ((ar >> 1) & 3);
    int arow = row0 + ar; if (arow > M - 1) arow = M - 1;
    const _Float16* aSrc = h0 + (long long)arow * 128 + ag * 8;

    const int bc0 = t >> 2;
    const int gb = ap ^ ((bc0 >> 1) & 3);

    const int w = t >> 6, lane = t & 63;
    const int wr = w >> 1, wc = w & 1;
    const int lrow = lane & 15, g = lane >> 4;

    unsigned int offA[2], offB[8];
    #pragma unroll
    for (int rt = 0; rt < 2; ++rt) {
        int r = wr * 32 + rt * 16 + lrow;
        offA[rt] = r * 64 + (g ^ ((r >> 1) & 3)) * 16;
    }
    #pragma unroll
    for (int ct = 0; ct < 8; ++ct) {
        int cidx = wc * 128 + ct * 16 + lrow;
        offB[ct] = cidx * 64 + (g ^ ((cidx >> 1) & 3)) * 16;
    }

    f32x4 acc[2][8];
    #pragma unroll
    for (int i = 0; i < 2; ++i)
        #pragma unroll
        for (int j = 0; j < 8; ++j)
            acc[i][j] = (f32x4){0.f, 0.f, 0.f, 0.f};

#define STORE_ACTS(BIAS)                                                     \
    {                                                                        \
        _Pragma("unroll")                                                    \
        for (int ct = 0; ct < 8; ++ct) {                                     \
            int col = wc * 128 + ct * 16 + lrow;                             \
            float bb = (BIAS)[col];                                          \
            int chk = col >> 5, kk = col & 31;                               \
            int kg = kk >> 3, ke = kk & 7;                                   \
            _Pragma("unroll")                                                \
            for (int rt = 0; rt < 2; ++rt) {                                 \
                _Pragma("unroll")                                            \
                for (int jj = 0; jj < 4; ++jj) {                             \
                    int rowl = wr * 32 + rt * 16 + g * 4 + jj;               \
                    int slot = kg ^ ((rowl >> 1) & 3);                       \
                    sA[chk * 2048 + rowl * 32 + slot * 8 + ke] =             \
                        (_Float16)fmaxf(acc[rt][ct][jj] + bb, 0.f);          \
                    acc[rt][ct][jj] = 0.f;                                   \
                }                                                            \
            }                                                                \
        }                                                                    \
    }

#define MFMA_CHUNK(KC)                                                       \
    {                                                                        \
        half8 a[2], b[8];                                                    \
        _Pragma("unroll")                                                    \
        for (int rt = 0; rt < 2; ++rt)                                       \
            a[rt] = *reinterpret_cast<const half8*>(                         \
                (const char*)sA + (KC) * 4096 + offA[rt]);                   \
        _Pragma("unroll")                                                    \
        for (int ct = 0; ct < 8; ++ct)                                       \
            b[ct] = *reinterpret_cast<const half8*>(                         \
                (const char*)sB + offB[ct]);                                 \
        _Pragma("unroll")                                                    \
        for (int rt = 0; rt < 2; ++rt)                                       \
            _Pragma("unroll")                                                \
            for (int ct = 0; ct < 8; ++ct)                                   \
                acc[rt][ct] = __builtin_amdgcn_mfma_f32_16x16x32_f16(        \
                    a[rt], b[ct], acc[rt][ct], 0, 0, 0);                     \
    }

    // layer 1: A from global h0 (K=128, 4 chunks)
    #pragma unroll
    for (int kc = 0; kc < 4; ++kc) {
        __syncthreads();
        gload16(aSrc + kc * 32, (char*)sA + kc * 4096 + t * 16);
        #pragma unroll
        for (int j = 0; j < 4; ++j)
            gload16(WT1 + (long long)(bc0 + j * 64) * 128 + gb * 8 + kc * 32,
                    (char*)sB + j * 4096 + t * 16);
        __syncthreads();
        MFMA_CHUNK(kc);
    }
    __syncthreads();
    STORE_ACTS(b1);

    // layer 2
    #pragma unroll
    for (int kc = 0; kc < 8; ++kc) {
        __syncthreads();
        #pragma unroll
        for (int j = 0; j < 4; ++j)
            gload16(WT2 + (long long)(bc0 + j * 64) * 256 + gb * 8 + kc * 32,
                    (char*)sB + j * 4096 + t * 16);
        __syncthreads();
        MFMA_CHUNK(kc);
    }
    __syncthreads();
    STORE_ACTS(b2);

    // layer 3
    #pragma unroll
    for (int kc = 0; kc < 8; ++kc) {
        __syncthreads();
        #pragma unroll
        for (int j = 0; j < 4; ++j)
            gload16(WT3 + (long long)(bc0 + j * 64) * 256 + gb * 8 + kc * 32,
                    (char*)sB + j * 4096 + t * 16);
        __syncthreads();
        MFMA_CHUNK(kc);
    }

    // epilogue: bias+relu, dot W4, block reduce
    float sum = 0.f;
    #pragma unroll
    for (int ct = 0; ct < 8; ++ct) {
        int col = wc * 128 + ct * 16 + lrow;
        float bb = b3[col];
        float w4 = W4[col];
        #pragma unroll
        for (int rt = 0; rt < 2; ++rt) {
            #pragma unroll
            for (int jj = 0; jj < 4; ++jj) {
                int row = row0 + wr * 32 + rt * 16 + g * 4 + jj;
                if (row < M) {
                    float v = fmaxf(acc[rt][ct][jj] + bb, 0.f);
                    sum += v * w4;
                }
            }
        }
    }
    #pragma unroll
    for (int off = 32; off > 0; off >>= 1) sum += __shfl_xor(sum, off, 64);
    if (lane == 0) redf[w] = sum;
    __syncthreads();
    if (t == 0) partials[blockIdx.x] = redf[0] + redf[1] + redf[2] + redf[3];
#undef STORE_ACTS
#undef MFMA_CHUNK
}

// ---------------------------------------------------------------------------
// K6: final mean: out = sum(partials)/N + b4
// ---------------------------------------------------------------------------
__global__ __launch_bounds__(256) void final_kernel(
    const float* __restrict__ partials, int n,
    const float* __restrict__ b4, float* __restrict__ out)
{
    __shared__ float buf[256];
    float s = 0.f;
    for (int i = threadIdx.x; i < n; i += 256) s += partials[i];
    buf[threadIdx.x] = s;
    __syncthreads();
    for (int off = 128; off > 0; off >>= 1) {
        if (threadIdx.x < off) buf[threadIdx.x] += buf[threadIdx.x + off];
        __syncthreads();
    }
    if (threadIdx.x == 0) out[0] = buf[0] / (float)N_NODES + b4[0];
}

// ---------------------------------------------------------------------------
extern "C" void kernel_launch(void* const* d_in, const int* in_sizes, int n_in,
                              void* d_out, int out_size, void* d_ws, size_t ws_size,
                              hipStream_t stream)
{
    const float* x   = (const float*)d_in[0];
    const float* pos = (const float*)d_in[1];
    const float* z   = (const float*)d_in[2];
    const int*   ei  = (const int*)d_in[3];
    const float* W1  = (const float*)d_in[4];
    const float* b1  = (const float*)d_in[5];
    const float* W2  = (const float*)d_in[6];
    const float* b2  = (const float*)d_in[7];
    const float* W3  = (const float*)d_in[8];
    const float* b3  = (const float*)d_in[9];
    const float* W4  = (const float*)d_in[10];
    const float* b4  = (const float*)d_in[11];
    float* out = (float*)d_out;

    char* ws = (char*)d_ws;
    _Float16*     feats    = (_Float16*)    (ws);              //  25,600,000
    _Float16*     h0       = (_Float16*)    (ws + 25600000);   //  25,600,000
    int*          gcnt     = (int*)         (ws + 51200000);   //   3,201,024
    int*          gbase    = (int*)         (ws + 54401024);   //   3,201,024
    int*          btot     = (int*)         (ws + 57602048);   //       6,252
    int*          bbase    = (int*)         (ws + 57608304);   //       6,256
    unsigned int* bucketed = (unsigned int*)(ws + 57614560);   //  12,800,000
    _Float16*     WT1      = (_Float16*)    (ws + 70414560);   //      65,536
    _Float16*     WT2      = (_Float16*)    (ws + 70480096);   //     131,072
    _Float16*     WT3      = (_Float16*)    (ws + 70611168);   //     131,072
    float*        partials = (float*)       (ws + 70742240);   //       6,252

    const int gblocks = (N_NODES + 63) / 64;   // 1563

    // weight prep
    wprep_kernel<<<(128 * 256 + 255) / 256, 256, 0, stream>>>(W1, 128, WT1);
    wprep_kernel<<<(256 * 256 + 255) / 256, 256, 0, stream>>>(W2, 256, WT2);
    wprep_kernel<<<(256 * 256 + 255) / 256, 256, 0, stream>>>(W3, 256, WT3);

    // pack features (f16)
    pack_kernel<<<(N_NODES * 128 + 255) / 256, 256, 0, stream>>>(x, pos, z, feats);

    // CSR build via two-level bucketing (LDS int atomics only)
    coarse_hist_kernel<<<NBLK_E, 256, 0, stream>>>(ei, gcnt);
    bucket_tot_kernel<<<NBUCK, 256, 0, stream>>>(gcnt, btot);
    scan_buckets_kernel<<<1, 1024, 0, stream>>>(btot, bbase);
    colscan_kernel<<<NBUCK, 256, 0, stream>>>(gcnt, bbase, gbase);
    bucket_scatter_kernel<<<NBLK_E, 256, 0, stream>>>(ei, gbase, bucketed);

    // per-bucket counting sort + aggregate + normalize -> h0 (f16)
    sortagg_kernel<<<NBUCK, 256, 0, stream>>>(bbase, bucketed, (const uint2*)feats, h0);

    // fused MLP (3 layers + W4 dot) -> partials
    fused_mlp_kernel<<<gblocks, 256, 0, stream>>>(
        h0, WT1, b1, WT2, b2, WT3, b3, W4, partials, N_NODES);

    // final mean
    final_kernel<<<1, 256, 0, stream>>>(partials, gblocks, b4, out);
}